// Round 10
// baseline (184.789 us; speedup 1.0000x reference)
//
#include <hip/hip_runtime.h>
#include <math.h>

typedef __bf16 bf16;
typedef __attribute__((ext_vector_type(8))) __bf16 bf16x8;
typedef __attribute__((ext_vector_type(4))) float f32x4;

#define LOG2E 1.44269504088896f
#define SCALE 0.125f   // 1/sqrt(64)

__device__ inline f32x4 mfma16(bf16x8 a, bf16x8 b, f32x4 c) {
    return __builtin_amdgcn_mfma_f32_16x16x32_bf16(a, b, c, 0, 0, 0);
}
__device__ inline bf16x8 cvt8(float4 v0, float4 v1) {
    bf16x8 o;
    o[0] = (bf16)v0.x; o[1] = (bf16)v0.y; o[2] = (bf16)v0.z; o[3] = (bf16)v0.w;
    o[4] = (bf16)v1.x; o[5] = (bf16)v1.y; o[6] = (bf16)v1.z; o[7] = (bf16)v1.w;
    return o;
}

// ---------------------------------------------------------- QKV GEMM --------
// 64x128 tile, grid (64,12)=768 blocks (~3/CU), 4 waves (2x2 of 32x64), BK=64.
// Reads f32 h + f32 W{q,k,v}, converts during staging. Q,K -> (B,H,N,64);
// V -> transposed (B,H,64,N). Epilogue through LDS, coalesced bf16x8 stores.
__global__ __launch_bounds__(256) void gemm_qkv_kernel(
        const float* __restrict__ A, const float* __restrict__ Wq,
        const float* __restrict__ Wk, const float* __restrict__ Wv,
        const float* __restrict__ bq, const float* __restrict__ bk,
        const float* __restrict__ bv,
        bf16* __restrict__ Qb, bf16* __restrict__ Kb, bf16* __restrict__ Vt) {
    __shared__ bf16 smem[64 * 72 + 128 * 72];
    bf16 (*Asm)[72] = (bf16(*)[72])smem;
    bf16 (*Bsm)[72] = (bf16(*)[72])(smem + 64 * 72);
    int t = threadIdx.x, w = t >> 6, lane = t & 63, g = lane >> 4, lo = lane & 15;
    int rowbase = blockIdx.x * 64, colbase = blockIdx.y * 128;
    int proj = colbase >> 9, wcol = colbase & 511;
    const float* Wsrc = (proj == 0) ? Wq : (proj == 1 ? Wk : Wv);
    const float* bsrc = (proj == 0) ? bq : (proj == 1 ? bk : bv);
    int wr = (w >> 1) * 32, wc = (w & 1) * 64;
    f32x4 acc[2][4] = {};
    int arow = t >> 2, acol = (t & 3) * 16;
    int brow = t >> 1, bcol = (t & 1) * 32;
    for (int kb = 0; kb < 512; kb += 64) {
        __syncthreads();
        {
            const float4* as = (const float4*)&A[(size_t)(rowbase + arow) * 512 + kb + acol];
            *(bf16x8*)&Asm[arow][acol]     = cvt8(as[0], as[1]);
            *(bf16x8*)&Asm[arow][acol + 8] = cvt8(as[2], as[3]);
            const float4* bs = (const float4*)&Wsrc[(size_t)(wcol + brow) * 512 + kb + bcol];
            *(bf16x8*)&Bsm[brow][bcol]      = cvt8(bs[0], bs[1]);
            *(bf16x8*)&Bsm[brow][bcol + 8]  = cvt8(bs[2], bs[3]);
            *(bf16x8*)&Bsm[brow][bcol + 16] = cvt8(bs[4], bs[5]);
            *(bf16x8*)&Bsm[brow][bcol + 24] = cvt8(bs[6], bs[7]);
        }
        __syncthreads();
        for (int kk = 0; kk < 64; kk += 32) {
            bf16x8 af[2], bfr[4];
            for (int m = 0; m < 2; m++) af[m]  = *(const bf16x8*)&Asm[wr + 16 * m + lo][kk + 8 * g];
            for (int n = 0; n < 4; n++) bfr[n] = *(const bf16x8*)&Bsm[wc + 16 * n + lo][kk + 8 * g];
            for (int m = 0; m < 2; m++)
                for (int n = 0; n < 4; n++)
                    acc[m][n] = mfma16(af[m], bfr[n], acc[m][n]);
        }
    }
    __syncthreads();
    bf16 (*Cl)[132] = (bf16(*)[132])smem;    // 64x132x2 = 16.9KB, aliases smem
    for (int n = 0; n < 4; n++) {
        float bv = bsrc[wcol + wc + 16 * n + lo];
        for (int m = 0; m < 2; m++)
            for (int r = 0; r < 4; r++)
                Cl[wr + 16 * m + 4 * g + r][wc + 16 * n + lo] = (bf16)(acc[m][n][r] + bv);
    }
    __syncthreads();
    int h0 = (colbase >> 6) & 7;
    int bidx = rowbase >> 10, i0g = rowbase & 1023;
    if (proj < 2) {
        int row = t >> 2, q4 = t & 3;
        int head = h0 + (q4 >> 1), d0 = (q4 & 1) * 32;
        bf16* dst = (proj == 0 ? Qb : Kb) +
                    ((size_t)(bidx * 8 + head) * 1024 + i0g + row) * 64 + d0;
        for (int ch = 0; ch < 4; ch++)
            *(bf16x8*)&dst[ch * 8] = *(const bf16x8*)&Cl[row][(q4 >> 1) * 64 + d0 + ch * 8];
    } else {
        int dcol = t >> 1, ihalf = t & 1;
        int head = h0 + (dcol >> 6), d = dcol & 63;
        bf16* dst = Vt + ((size_t)(bidx * 8 + head) * 64 + d) * 1024 + i0g + ihalf * 32;
        for (int ch = 0; ch < 4; ch++) {
            bf16x8 v;
            for (int q = 0; q < 8; q++) v[q] = Cl[ihalf * 32 + ch * 8 + q][dcol];
            *(bf16x8*)&dst[ch * 8] = v;
        }
    }
}

// ----------------------------------------------------- fused attention ------
// Fixed-max flash attention, KV-split=2 (4096 waves -> 4 waves/SIMD).
// geo MFMA emits u = -d^2/2 via hi/lo const k-slots computed inline from f32 x;
// K-slot pairing: A:[s_hi,s_lo,1,1] x B:[1,1,s_hi,s_lo] -> s_i + s_j.
// bias = sum_c alpha_c * e^(u/sigma_c^2), clamp u<=0. Row sums via ones-MFMA.
// Writes unnormalized f32 o_part + l_part; gemm_out fuses the merge.
__global__ __launch_bounds__(256) void attn_kernel(
        const bf16* __restrict__ Qb, const bf16* __restrict__ Kb,
        const bf16* __restrict__ Vt, const float* __restrict__ x,
        const float* __restrict__ alpha, const float* __restrict__ log_sigma,
        float* __restrict__ o_part, float* __restrict__ l_part) {
    __shared__ bf16 Klds[64][72];
    __shared__ bf16 VTlds[64][72];
    __shared__ bf16 Xlds[64][80];    // comp c at cols c*24: 16 x, [1,1,s_hi,s_lo,0,0,0,0]
    __shared__ bf16 Plds[4][16][72];

    int t = threadIdx.x;
    int w = t >> 6, lane = t & 63, g = lane >> 4, lo = lane & 15;
    int zz = blockIdx.z;
    int b = zz >> 1, split = zz & 1;
    int hh = blockIdx.y;
    int i0 = blockIdx.x * 64 + w * 16;

    float c1 = SCALE * LOG2E;
    float k2[3], alf[3];
    for (int c = 0; c < 3; c++) {
        float sg = fmaxf(expf(log_sigma[hh * 3 + c]), 1e-4f);
        k2[c] = LOG2E / (sg * sg);
        alf[c] = alpha[hh * 3 + c] * LOG2E;
    }

    const bf16* Qbase = Qb + ((size_t)(b * 8 + hh) * 1024 + i0) * 64;
    bf16x8 qa[2];
    qa[0] = *(const bf16x8*)&Qbase[lo * 64 + 8 * g];
    qa[1] = *(const bf16x8*)&Qbase[lo * 64 + 32 + 8 * g];

    // A-side geo fragments: g<2: bf16(x); g==2: [s_hi,s_lo,1,1,0..]; g==3: 0
    bf16x8 xqa[3];
    for (int c = 0; c < 3; c++) {
        bf16x8 v = {};
        if (g < 2) {
            const float4* xs = (const float4*)&x[((size_t)(b << 10) + i0 + lo) * 48 + c * 16 + 8 * g];
            v = cvt8(xs[0], xs[1]);
        } else if (g == 2) {
            const float* xr = &x[((size_t)(b << 10) + i0 + lo) * 48 + c * 16];
            float s = 0.0f;
            for (int k = 0; k < 16; k++) {
                float vv = (float)(bf16)xr[k];
                s += vv * vv;
            }
            s = -0.5f * s;
            bf16 sh = (bf16)s;
            v[0] = sh;
            v[1] = (bf16)(s - (float)sh);
            v[2] = (bf16)1.0f;
            v[3] = (bf16)1.0f;
        }
        xqa[c] = v;
    }

    bf16x8 ones;
    for (int e = 0; e < 8; e++) ones[e] = (bf16)1.0f;
    f32x4 o[4] = {};
    f32x4 lacc = {};

    // zero the pad cols 72..79 once (g==3 B-reads for c==2 land here; must be
    // finite since 0*Inf = NaN)
    for (int idx = t; idx < 64; idx += 256)
        *(uint4*)&Xlds[idx][72] = (uint4){0, 0, 0, 0};

    int sr = t >> 2, sc = (t & 3) * 16;
    int jb = split * 512;
    for (int j0 = jb; j0 < jb + 512; j0 += 64) {
        __syncthreads();   // prev tile reads done (covers pad-zero on iter 0)
        const bf16* Kbase = Kb + ((size_t)(b * 8 + hh) * 1024 + j0) * 64;
        *(bf16x8*)&Klds[sr][sc]     = *(const bf16x8*)&Kbase[sr * 64 + sc];
        *(bf16x8*)&Klds[sr][sc + 8] = *(const bf16x8*)&Kbase[sr * 64 + sc + 8];
        const bf16* Vbase = Vt + ((size_t)(b * 8 + hh) * 64) * 1024 + j0;
        *(bf16x8*)&VTlds[sr][sc]     = *(const bf16x8*)&Vbase[sr * 1024 + sc];
        *(bf16x8*)&VTlds[sr][sc + 8] = *(const bf16x8*)&Vbase[sr * 1024 + sc + 8];
        if (t < 192) {
            int xr = t / 3, c = t - xr * 3;
            const float4* xs = (const float4*)&x[((size_t)(b << 10) + j0 + xr) * 48 + c * 16];
            bf16x8 d0 = cvt8(xs[0], xs[1]);
            bf16x8 d1 = cvt8(xs[2], xs[3]);
            *(bf16x8*)&Xlds[xr][c * 24]     = d0;
            *(bf16x8*)&Xlds[xr][c * 24 + 8] = d1;
            float s = 0.0f;
            for (int k = 0; k < 8; k++) {
                float a0 = (float)d0[k], a1 = (float)d1[k];
                s += a0 * a0 + a1 * a1;
            }
            s = -0.5f * s;
            bf16 sh = (bf16)s;
            bf16x8 cst = {};
            cst[0] = (bf16)1.0f;             // pairs with A slot s_hi
            cst[1] = (bf16)1.0f;             // pairs with A slot s_lo
            cst[2] = sh;                     // pairs with A slot 1
            cst[3] = (bf16)(s - (float)sh);  // pairs with A slot 1
            *(bf16x8*)&Xlds[xr][c * 24 + 16] = cst;
        }
        __syncthreads();

        for (int tt = 0; tt < 4; tt++) {
            f32x4 acc = {};
            bf16x8 kb0 = *(const bf16x8*)&Klds[16 * tt + lo][8 * g];
            bf16x8 kb1 = *(const bf16x8*)&Klds[16 * tt + lo][32 + 8 * g];
            acc = mfma16(qa[0], kb0, acc);
            acc = mfma16(qa[1], kb1, acc);
            f32x4 z0 = {}, z1 = {}, z2 = {};
            f32x4 e0 = mfma16(xqa[0], *(const bf16x8*)&Xlds[16 * tt + lo][8 * g], z0);
            f32x4 e1 = mfma16(xqa[1], *(const bf16x8*)&Xlds[16 * tt + lo][24 + 8 * g], z1);
            f32x4 e2 = mfma16(xqa[2], *(const bf16x8*)&Xlds[16 * tt + lo][48 + 8 * g], z2);
            for (int r = 0; r < 4; r++) {
                float t0 = alf[0] * exp2f(k2[0] * fminf(e0[r], 0.0f));
                t0 = fmaf(alf[1], exp2f(k2[1] * fminf(e1[r], 0.0f)), t0);
                t0 = fmaf(alf[2], exp2f(k2[2] * fminf(e2[r], 0.0f)), t0);
                float p = exp2f(fmaf(acc[r], c1, t0));
                Plds[w][4 * g + r][16 * tt + lo] = (bf16)p;
            }
        }

        bf16x8 pa0 = *(const bf16x8*)&Plds[w][lo][8 * g];
        bf16x8 pa1 = *(const bf16x8*)&Plds[w][lo][32 + 8 * g];
        lacc = mfma16(pa0, ones, lacc);
        lacc = mfma16(pa1, ones, lacc);
        for (int td = 0; td < 4; td++) {
            bf16x8 vb0 = *(const bf16x8*)&VTlds[16 * td + lo][8 * g];
            bf16x8 vb1 = *(const bf16x8*)&VTlds[16 * td + lo][32 + 8 * g];
            o[td] = mfma16(pa0, vb0, o[td]);
            o[td] = mfma16(pa1, vb1, o[td]);
        }
    }

    for (int td = 0; td < 4; td++)
        for (int r = 0; r < 4; r++) {
            size_t rowg = (size_t)(b * 8 + hh) * 1024 + i0 + 4 * g + r;
            o_part[((size_t)split * 32768 + rowg) * 64 + 16 * td + lo] = o[td][r];
        }
    if (lo == 0)
        for (int r = 0; r < 4; r++) {
            size_t rowg = (size_t)(b * 8 + hh) * 1024 + i0 + 4 * g + r;
            l_part[(size_t)split * 32768 + rowg] = lacc[r];
        }
}

// ------------------------------------------- output GEMM + fused merge ------
// 64x64 tile, grid (64,8)=512 blocks (2/CU), BK=64 (one head per kb step).
// A-tile staged by merging the two KV-splits + normalizing to bf16; B from
// f32 Wo. Direct f32 epilogue.
__global__ __launch_bounds__(256) void gemm_out_kernel(
        const float* __restrict__ o_part, const float* __restrict__ l_part,
        const float* __restrict__ Wo, const float* __restrict__ bo,
        float* __restrict__ out) {
    __shared__ bf16 Asm[64][72];
    __shared__ bf16 Bsm[64][72];
    int t = threadIdx.x, w = t >> 6, lane = t & 63, g = lane >> 4, lo = lane & 15;
    int rowbase = blockIdx.x * 64, colbase = blockIdx.y * 64;
    int wr = (w >> 1) * 32, wc = (w & 1) * 32;
    f32x4 acc[2][2] = {};
    int srow = t >> 2, scol = (t & 3) * 16;
    for (int kb = 0; kb < 512; kb += 64) {
        __syncthreads();
        {
            int hh = kb >> 6;
            int n = rowbase + srow;
            size_t rowg = (size_t)((n >> 10) * 8 + hh) * 1024 + (n & 1023);
            const float* p0 = &o_part[rowg * 64 + scol];
            const float* p1 = &o_part[((size_t)32768 + rowg) * 64 + scol];
            float inv = 1.0f / (l_part[rowg] + l_part[32768 + rowg]);
            float4 a0 = ((const float4*)p0)[0], a1 = ((const float4*)p0)[1];
            float4 a2 = ((const float4*)p0)[2], a3 = ((const float4*)p0)[3];
            float4 c0 = ((const float4*)p1)[0], c1 = ((const float4*)p1)[1];
            float4 c2 = ((const float4*)p1)[2], c3 = ((const float4*)p1)[3];
            bf16x8 r0, r1;
            r0[0] = (bf16)((a0.x + c0.x) * inv); r0[1] = (bf16)((a0.y + c0.y) * inv);
            r0[2] = (bf16)((a0.z + c0.z) * inv); r0[3] = (bf16)((a0.w + c0.w) * inv);
            r0[4] = (bf16)((a1.x + c1.x) * inv); r0[5] = (bf16)((a1.y + c1.y) * inv);
            r0[6] = (bf16)((a1.z + c1.z) * inv); r0[7] = (bf16)((a1.w + c1.w) * inv);
            r1[0] = (bf16)((a2.x + c2.x) * inv); r1[1] = (bf16)((a2.y + c2.y) * inv);
            r1[2] = (bf16)((a2.z + c2.z) * inv); r1[3] = (bf16)((a2.w + c2.w) * inv);
            r1[4] = (bf16)((a3.x + c3.x) * inv); r1[5] = (bf16)((a3.y + c3.y) * inv);
            r1[6] = (bf16)((a3.z + c3.z) * inv); r1[7] = (bf16)((a3.w + c3.w) * inv);
            *(bf16x8*)&Asm[srow][scol]     = r0;
            *(bf16x8*)&Asm[srow][scol + 8] = r1;
        }
        {
            const float4* bs = (const float4*)&Wo[(size_t)(colbase + srow) * 512 + kb + scol];
            *(bf16x8*)&Bsm[srow][scol]     = cvt8(bs[0], bs[1]);
            *(bf16x8*)&Bsm[srow][scol + 8] = cvt8(bs[2], bs[3]);
        }
        __syncthreads();
        for (int kk = 0; kk < 64; kk += 32) {
            bf16x8 af[2], bfr[2];
            for (int m = 0; m < 2; m++) af[m]  = *(const bf16x8*)&Asm[wr + 16 * m + lo][kk + 8 * g];
            for (int n = 0; n < 2; n++) bfr[n] = *(const bf16x8*)&Bsm[wc + 16 * n + lo][kk + 8 * g];
            for (int m = 0; m < 2; m++)
                for (int n = 0; n < 2; n++)
                    acc[m][n] = mfma16(af[m], bfr[n], acc[m][n]);
        }
    }
    for (int n = 0; n < 2; n++) {
        int mcol = colbase + wc + 16 * n + lo;
        float bv = bo[mcol];
        for (int m = 0; m < 2; m++)
            for (int r = 0; r < 4; r++)
                out[(size_t)(rowbase + wr + 16 * m + 4 * g + r) * 512 + mcol] =
                    acc[m][n][r] + bv;
    }
}

// ---------------------------------------------------------------- launch ----
extern "C" void kernel_launch(void* const* d_in, const int* in_sizes, int n_in,
                              void* d_out, int out_size, void* d_ws, size_t ws_size,
                              hipStream_t stream) {
    const float* h  = (const float*)d_in[0];
    const float* x  = (const float*)d_in[1];
    const float* Wq = (const float*)d_in[2];
    const float* bq = (const float*)d_in[3];
    const float* Wk = (const float*)d_in[4];
    const float* bk = (const float*)d_in[5];
    const float* Wv = (const float*)d_in[6];
    const float* bv = (const float*)d_in[7];
    const float* Wo = (const float*)d_in[8];
    const float* bo = (const float*)d_in[9];
    const float* alpha     = (const float*)d_in[10];
    const float* log_sigma = (const float*)d_in[11];
    float* out = (float*)d_out;

    char* ws = (char*)d_ws;
    size_t off = 0;
    auto alloc = [&](size_t bytes) {
        char* p = ws + off;
        off += (bytes + 255) & ~(size_t)255;
        return p;
    };
    bf16*  Qb     = (bf16*)alloc((size_t)4 * 8 * 1024 * 64 * 2);
    bf16*  Kb     = (bf16*)alloc((size_t)4 * 8 * 1024 * 64 * 2);
    bf16*  Vt     = (bf16*)alloc((size_t)4 * 8 * 1024 * 64 * 2);
    float* o_part = (float*)alloc((size_t)2 * 32768 * 64 * 4);
    float* l_part = (float*)alloc((size_t)2 * 32768 * 4);

    gemm_qkv_kernel<<<dim3(64, 12), 256, 0, stream>>>(h, Wq, Wk, Wv, bq, bk, bv,
                                                      Qb, Kb, Vt);
    attn_kernel<<<dim3(16, 8, 8), 256, 0, stream>>>(
        Qb, Kb, Vt, x, alpha, log_sigma, o_part, l_part);
    gemm_out_kernel<<<dim3(64, 8), 256, 0, stream>>>(o_part, l_part, Wo, bo, out);
}

// Round 11
// 169.502 us; speedup vs baseline: 1.0902x; 1.0902x over previous
//
#include <hip/hip_runtime.h>
#include <math.h>

typedef __bf16 bf16;
typedef __attribute__((ext_vector_type(8))) __bf16 bf16x8;
typedef __attribute__((ext_vector_type(4))) float f32x4;

#define LOG2E 1.44269504088896f
#define SCALE 0.125f   // 1/sqrt(64)

__device__ inline f32x4 mfma16(bf16x8 a, bf16x8 b, f32x4 c) {
    return __builtin_amdgcn_mfma_f32_16x16x32_bf16(a, b, c, 0, 0, 0);
}
__device__ inline bf16x8 cvt8(float4 v0, float4 v1) {
    bf16x8 o;
    o[0] = (bf16)v0.x; o[1] = (bf16)v0.y; o[2] = (bf16)v0.z; o[3] = (bf16)v0.w;
    o[4] = (bf16)v1.x; o[5] = (bf16)v1.y; o[6] = (bf16)v1.z; o[7] = (bf16)v1.w;
    return o;
}
// raw v_exp_f32 (2^x): args here are bounded above (clamped exponents), and
// underflow flushes to 0 which is the mathematically-desired limit. Avoids
// libm exp2f's multi-instruction denormal fixup path.
__device__ inline float fastexp2(float x) {
    float r;
    asm("v_exp_f32 %0, %1" : "=v"(r) : "v"(x));
    return r;
}

// ---------------------------------------------------------- QKV GEMM --------
// 64x128 tile, grid (64,12)=768 blocks (~3/CU), 4 waves (2x2 of 32x64), BK=64.
// Reads f32 h + f32 W{q,k,v}, converts during staging. Q,K -> (B,H,N,64);
// V -> transposed (B,H,64,N). Epilogue through LDS, coalesced bf16x8 stores.
__global__ __launch_bounds__(256) void gemm_qkv_kernel(
        const float* __restrict__ A, const float* __restrict__ Wq,
        const float* __restrict__ Wk, const float* __restrict__ Wv,
        const float* __restrict__ bq, const float* __restrict__ bk,
        const float* __restrict__ bv,
        bf16* __restrict__ Qb, bf16* __restrict__ Kb, bf16* __restrict__ Vt) {
    __shared__ bf16 smem[64 * 72 + 128 * 72];
    bf16 (*Asm)[72] = (bf16(*)[72])smem;
    bf16 (*Bsm)[72] = (bf16(*)[72])(smem + 64 * 72);
    int t = threadIdx.x, w = t >> 6, lane = t & 63, g = lane >> 4, lo = lane & 15;
    int rowbase = blockIdx.x * 64, colbase = blockIdx.y * 128;
    int proj = colbase >> 9, wcol = colbase & 511;
    const float* Wsrc = (proj == 0) ? Wq : (proj == 1 ? Wk : Wv);
    const float* bsrc = (proj == 0) ? bq : (proj == 1 ? bk : bv);
    int wr = (w >> 1) * 32, wc = (w & 1) * 64;
    f32x4 acc[2][4] = {};
    int arow = t >> 2, acol = (t & 3) * 16;
    int brow = t >> 1, bcol = (t & 1) * 32;
    for (int kb = 0; kb < 512; kb += 64) {
        __syncthreads();
        {
            const float4* as = (const float4*)&A[(size_t)(rowbase + arow) * 512 + kb + acol];
            *(bf16x8*)&Asm[arow][acol]     = cvt8(as[0], as[1]);
            *(bf16x8*)&Asm[arow][acol + 8] = cvt8(as[2], as[3]);
            const float4* bs = (const float4*)&Wsrc[(size_t)(wcol + brow) * 512 + kb + bcol];
            *(bf16x8*)&Bsm[brow][bcol]      = cvt8(bs[0], bs[1]);
            *(bf16x8*)&Bsm[brow][bcol + 8]  = cvt8(bs[2], bs[3]);
            *(bf16x8*)&Bsm[brow][bcol + 16] = cvt8(bs[4], bs[5]);
            *(bf16x8*)&Bsm[brow][bcol + 24] = cvt8(bs[6], bs[7]);
        }
        __syncthreads();
        for (int kk = 0; kk < 64; kk += 32) {
            bf16x8 af[2], bfr[4];
            for (int m = 0; m < 2; m++) af[m]  = *(const bf16x8*)&Asm[wr + 16 * m + lo][kk + 8 * g];
            for (int n = 0; n < 4; n++) bfr[n] = *(const bf16x8*)&Bsm[wc + 16 * n + lo][kk + 8 * g];
            for (int m = 0; m < 2; m++)
                for (int n = 0; n < 4; n++)
                    acc[m][n] = mfma16(af[m], bfr[n], acc[m][n]);
        }
    }
    __syncthreads();
    bf16 (*Cl)[132] = (bf16(*)[132])smem;    // 64x132x2 = 16.9KB, aliases smem
    for (int n = 0; n < 4; n++) {
        float bv = bsrc[wcol + wc + 16 * n + lo];
        for (int m = 0; m < 2; m++)
            for (int r = 0; r < 4; r++)
                Cl[wr + 16 * m + 4 * g + r][wc + 16 * n + lo] = (bf16)(acc[m][n][r] + bv);
    }
    __syncthreads();
    int h0 = (colbase >> 6) & 7;
    int bidx = rowbase >> 10, i0g = rowbase & 1023;
    if (proj < 2) {
        int row = t >> 2, q4 = t & 3;
        int head = h0 + (q4 >> 1), d0 = (q4 & 1) * 32;
        bf16* dst = (proj == 0 ? Qb : Kb) +
                    ((size_t)(bidx * 8 + head) * 1024 + i0g + row) * 64 + d0;
        for (int ch = 0; ch < 4; ch++)
            *(bf16x8*)&dst[ch * 8] = *(const bf16x8*)&Cl[row][(q4 >> 1) * 64 + d0 + ch * 8];
    } else {
        int dcol = t >> 1, ihalf = t & 1;
        int head = h0 + (dcol >> 6), d = dcol & 63;
        bf16* dst = Vt + ((size_t)(bidx * 8 + head) * 64 + d) * 1024 + i0g + ihalf * 32;
        for (int ch = 0; ch < 4; ch++) {
            bf16x8 v;
            for (int q = 0; q < 8; q++) v[q] = Cl[ihalf * 32 + ch * 8 + q][dcol];
            *(bf16x8*)&dst[ch * 8] = v;
        }
    }
}

// ----------------------------------------------------- fused attention ------
// Fixed-max flash attention, KV-split=2 (4096 waves -> 4 waves/SIMD).
// geo MFMA emits u = -d^2/2 via hi/lo const k-slots computed inline from f32 x;
// K-slot pairing: A:[s_hi,s_lo,1,1] x B:[1,1,s_hi,s_lo] -> s_i + s_j.
// bias = sum_c alpha_c * e^(u/sigma_c^2), clamp u<=0. Row sums via ones-MFMA.
// exp via raw v_exp_f32; s_setprio around MFMA clusters.
__global__ __launch_bounds__(256) void attn_kernel(
        const bf16* __restrict__ Qb, const bf16* __restrict__ Kb,
        const bf16* __restrict__ Vt, const float* __restrict__ x,
        const float* __restrict__ alpha, const float* __restrict__ log_sigma,
        float* __restrict__ o_part, float* __restrict__ l_part) {
    __shared__ bf16 Klds[64][72];
    __shared__ bf16 VTlds[64][72];
    __shared__ bf16 Xlds[64][80];    // comp c at cols c*24: 16 x, [1,1,s_hi,s_lo,0,0,0,0]
    __shared__ bf16 Plds[4][16][72];

    int t = threadIdx.x;
    int w = t >> 6, lane = t & 63, g = lane >> 4, lo = lane & 15;
    int zz = blockIdx.z;
    int b = zz >> 1, split = zz & 1;
    int hh = blockIdx.y;
    int i0 = blockIdx.x * 64 + w * 16;

    float c1 = SCALE * LOG2E;
    float k2[3], alf[3];
    for (int c = 0; c < 3; c++) {
        float sg = fmaxf(expf(log_sigma[hh * 3 + c]), 1e-4f);
        k2[c] = LOG2E / (sg * sg);
        alf[c] = alpha[hh * 3 + c] * LOG2E;
    }

    const bf16* Qbase = Qb + ((size_t)(b * 8 + hh) * 1024 + i0) * 64;
    bf16x8 qa[2];
    qa[0] = *(const bf16x8*)&Qbase[lo * 64 + 8 * g];
    qa[1] = *(const bf16x8*)&Qbase[lo * 64 + 32 + 8 * g];

    // A-side geo fragments: g<2: bf16(x); g==2: [s_hi,s_lo,1,1,0..]; g==3: 0
    bf16x8 xqa[3];
    for (int c = 0; c < 3; c++) {
        bf16x8 v = {};
        if (g < 2) {
            const float4* xs = (const float4*)&x[((size_t)(b << 10) + i0 + lo) * 48 + c * 16 + 8 * g];
            v = cvt8(xs[0], xs[1]);
        } else if (g == 2) {
            const float* xr = &x[((size_t)(b << 10) + i0 + lo) * 48 + c * 16];
            float s = 0.0f;
            for (int k = 0; k < 16; k++) {
                float vv = (float)(bf16)xr[k];
                s += vv * vv;
            }
            s = -0.5f * s;
            bf16 sh = (bf16)s;
            v[0] = sh;
            v[1] = (bf16)(s - (float)sh);
            v[2] = (bf16)1.0f;
            v[3] = (bf16)1.0f;
        }
        xqa[c] = v;
    }

    bf16x8 ones;
    for (int e = 0; e < 8; e++) ones[e] = (bf16)1.0f;
    f32x4 o[4] = {};
    f32x4 lacc = {};

    // zero the pad cols 72..79 once (g==3 B-reads for c==2 land here; must be
    // finite since 0*Inf = NaN)
    for (int idx = t; idx < 64; idx += 256)
        *(uint4*)&Xlds[idx][72] = (uint4){0, 0, 0, 0};

    int sr = t >> 2, sc = (t & 3) * 16;
    int jb = split * 512;
    for (int j0 = jb; j0 < jb + 512; j0 += 64) {
        __syncthreads();   // prev tile reads done (covers pad-zero on iter 0)
        const bf16* Kbase = Kb + ((size_t)(b * 8 + hh) * 1024 + j0) * 64;
        *(bf16x8*)&Klds[sr][sc]     = *(const bf16x8*)&Kbase[sr * 64 + sc];
        *(bf16x8*)&Klds[sr][sc + 8] = *(const bf16x8*)&Kbase[sr * 64 + sc + 8];
        const bf16* Vbase = Vt + ((size_t)(b * 8 + hh) * 64) * 1024 + j0;
        *(bf16x8*)&VTlds[sr][sc]     = *(const bf16x8*)&Vbase[sr * 1024 + sc];
        *(bf16x8*)&VTlds[sr][sc + 8] = *(const bf16x8*)&Vbase[sr * 1024 + sc + 8];
        if (t < 192) {
            int xr = t / 3, c = t - xr * 3;
            const float4* xs = (const float4*)&x[((size_t)(b << 10) + j0 + xr) * 48 + c * 16];
            bf16x8 d0 = cvt8(xs[0], xs[1]);
            bf16x8 d1 = cvt8(xs[2], xs[3]);
            *(bf16x8*)&Xlds[xr][c * 24]     = d0;
            *(bf16x8*)&Xlds[xr][c * 24 + 8] = d1;
            float s = 0.0f;
            for (int k = 0; k < 8; k++) {
                float a0 = (float)d0[k], a1 = (float)d1[k];
                s += a0 * a0 + a1 * a1;
            }
            s = -0.5f * s;
            bf16 sh = (bf16)s;
            bf16x8 cst = {};
            cst[0] = (bf16)1.0f;             // pairs with A slot s_hi
            cst[1] = (bf16)1.0f;             // pairs with A slot s_lo
            cst[2] = sh;                     // pairs with A slot 1
            cst[3] = (bf16)(s - (float)sh);  // pairs with A slot 1
            *(bf16x8*)&Xlds[xr][c * 24 + 16] = cst;
        }
        __syncthreads();

        for (int tt = 0; tt < 4; tt++) {
            f32x4 acc = {};
            bf16x8 kb0 = *(const bf16x8*)&Klds[16 * tt + lo][8 * g];
            bf16x8 kb1 = *(const bf16x8*)&Klds[16 * tt + lo][32 + 8 * g];
            __builtin_amdgcn_s_setprio(1);
            acc = mfma16(qa[0], kb0, acc);
            acc = mfma16(qa[1], kb1, acc);
            f32x4 z0 = {}, z1 = {}, z2 = {};
            f32x4 e0 = mfma16(xqa[0], *(const bf16x8*)&Xlds[16 * tt + lo][8 * g], z0);
            f32x4 e1 = mfma16(xqa[1], *(const bf16x8*)&Xlds[16 * tt + lo][24 + 8 * g], z1);
            f32x4 e2 = mfma16(xqa[2], *(const bf16x8*)&Xlds[16 * tt + lo][48 + 8 * g], z2);
            __builtin_amdgcn_s_setprio(0);
            for (int r = 0; r < 4; r++) {
                float t0 = alf[0] * fastexp2(k2[0] * fminf(e0[r], 0.0f));
                t0 = fmaf(alf[1], fastexp2(k2[1] * fminf(e1[r], 0.0f)), t0);
                t0 = fmaf(alf[2], fastexp2(k2[2] * fminf(e2[r], 0.0f)), t0);
                float p = fastexp2(fmaf(acc[r], c1, t0));
                Plds[w][4 * g + r][16 * tt + lo] = (bf16)p;
            }
        }

        bf16x8 pa0 = *(const bf16x8*)&Plds[w][lo][8 * g];
        bf16x8 pa1 = *(const bf16x8*)&Plds[w][lo][32 + 8 * g];
        __builtin_amdgcn_s_setprio(1);
        lacc = mfma16(pa0, ones, lacc);
        lacc = mfma16(pa1, ones, lacc);
        for (int td = 0; td < 4; td++) {
            bf16x8 vb0 = *(const bf16x8*)&VTlds[16 * td + lo][8 * g];
            bf16x8 vb1 = *(const bf16x8*)&VTlds[16 * td + lo][32 + 8 * g];
            o[td] = mfma16(pa0, vb0, o[td]);
            o[td] = mfma16(pa1, vb1, o[td]);
        }
        __builtin_amdgcn_s_setprio(0);
    }

    for (int td = 0; td < 4; td++)
        for (int r = 0; r < 4; r++) {
            size_t rowg = (size_t)(b * 8 + hh) * 1024 + i0 + 4 * g + r;
            o_part[((size_t)split * 32768 + rowg) * 64 + 16 * td + lo] = o[td][r];
        }
    if (lo == 0)
        for (int r = 0; r < 4; r++) {
            size_t rowg = (size_t)(b * 8 + hh) * 1024 + i0 + 4 * g + r;
            l_part[(size_t)split * 32768 + rowg] = lacc[r];
        }
}

// ------------------------------------------- output GEMM + fused merge ------
// 64x64 tile, grid (64,8)=512 blocks (2/CU), BK=64 (one head per kb step).
// A-tile staged by merging the two KV-splits + normalizing to bf16; B from
// f32 Wo. Direct f32 epilogue.
__global__ __launch_bounds__(256) void gemm_out_kernel(
        const float* __restrict__ o_part, const float* __restrict__ l_part,
        const float* __restrict__ Wo, const float* __restrict__ bo,
        float* __restrict__ out) {
    __shared__ bf16 Asm[64][72];
    __shared__ bf16 Bsm[64][72];
    int t = threadIdx.x, w = t >> 6, lane = t & 63, g = lane >> 4, lo = lane & 15;
    int rowbase = blockIdx.x * 64, colbase = blockIdx.y * 64;
    int wr = (w >> 1) * 32, wc = (w & 1) * 32;
    f32x4 acc[2][2] = {};
    int srow = t >> 2, scol = (t & 3) * 16;
    for (int kb = 0; kb < 512; kb += 64) {
        __syncthreads();
        {
            int hh = kb >> 6;
            int n = rowbase + srow;
            size_t rowg = (size_t)((n >> 10) * 8 + hh) * 1024 + (n & 1023);
            const float* p0 = &o_part[rowg * 64 + scol];
            const float* p1 = &o_part[((size_t)32768 + rowg) * 64 + scol];
            float inv = 1.0f / (l_part[rowg] + l_part[32768 + rowg]);
            float4 a0 = ((const float4*)p0)[0], a1 = ((const float4*)p0)[1];
            float4 a2 = ((const float4*)p0)[2], a3 = ((const float4*)p0)[3];
            float4 c0 = ((const float4*)p1)[0], c1 = ((const float4*)p1)[1];
            float4 c2 = ((const float4*)p1)[2], c3 = ((const float4*)p1)[3];
            bf16x8 r0, r1;
            r0[0] = (bf16)((a0.x + c0.x) * inv); r0[1] = (bf16)((a0.y + c0.y) * inv);
            r0[2] = (bf16)((a0.z + c0.z) * inv); r0[3] = (bf16)((a0.w + c0.w) * inv);
            r0[4] = (bf16)((a1.x + c1.x) * inv); r0[5] = (bf16)((a1.y + c1.y) * inv);
            r0[6] = (bf16)((a1.z + c1.z) * inv); r0[7] = (bf16)((a1.w + c1.w) * inv);
            r1[0] = (bf16)((a2.x + c2.x) * inv); r1[1] = (bf16)((a2.y + c2.y) * inv);
            r1[2] = (bf16)((a2.z + c2.z) * inv); r1[3] = (bf16)((a2.w + c2.w) * inv);
            r1[4] = (bf16)((a3.x + c3.x) * inv); r1[5] = (bf16)((a3.y + c3.y) * inv);
            r1[6] = (bf16)((a3.z + c3.z) * inv); r1[7] = (bf16)((a3.w + c3.w) * inv);
            *(bf16x8*)&Asm[srow][scol]     = r0;
            *(bf16x8*)&Asm[srow][scol + 8] = r1;
        }
        {
            const float4* bs = (const float4*)&Wo[(size_t)(colbase + srow) * 512 + kb + scol];
            *(bf16x8*)&Bsm[srow][scol]     = cvt8(bs[0], bs[1]);
            *(bf16x8*)&Bsm[srow][scol + 8] = cvt8(bs[2], bs[3]);
        }
        __syncthreads();
        for (int kk = 0; kk < 64; kk += 32) {
            bf16x8 af[2], bfr[2];
            for (int m = 0; m < 2; m++) af[m]  = *(const bf16x8*)&Asm[wr + 16 * m + lo][kk + 8 * g];
            for (int n = 0; n < 2; n++) bfr[n] = *(const bf16x8*)&Bsm[wc + 16 * n + lo][kk + 8 * g];
            for (int m = 0; m < 2; m++)
                for (int n = 0; n < 2; n++)
                    acc[m][n] = mfma16(af[m], bfr[n], acc[m][n]);
        }
    }
    for (int n = 0; n < 2; n++) {
        int mcol = colbase + wc + 16 * n + lo;
        float bv = bo[mcol];
        for (int m = 0; m < 2; m++)
            for (int r = 0; r < 4; r++)
                out[(size_t)(rowbase + wr + 16 * m + 4 * g + r) * 512 + mcol] =
                    acc[m][n][r] + bv;
    }
}

// ---------------------------------------------------------------- launch ----
extern "C" void kernel_launch(void* const* d_in, const int* in_sizes, int n_in,
                              void* d_out, int out_size, void* d_ws, size_t ws_size,
                              hipStream_t stream) {
    const float* h  = (const float*)d_in[0];
    const float* x  = (const float*)d_in[1];
    const float* Wq = (const float*)d_in[2];
    const float* bq = (const float*)d_in[3];
    const float* Wk = (const float*)d_in[4];
    const float* bk = (const float*)d_in[5];
    const float* Wv = (const float*)d_in[6];
    const float* bv = (const float*)d_in[7];
    const float* Wo = (const float*)d_in[8];
    const float* bo = (const float*)d_in[9];
    const float* alpha     = (const float*)d_in[10];
    const float* log_sigma = (const float*)d_in[11];
    float* out = (float*)d_out;

    char* ws = (char*)d_ws;
    size_t off = 0;
    auto alloc = [&](size_t bytes) {
        char* p = ws + off;
        off += (bytes + 255) & ~(size_t)255;
        return p;
    };
    bf16*  Qb     = (bf16*)alloc((size_t)4 * 8 * 1024 * 64 * 2);
    bf16*  Kb     = (bf16*)alloc((size_t)4 * 8 * 1024 * 64 * 2);
    bf16*  Vt     = (bf16*)alloc((size_t)4 * 8 * 1024 * 64 * 2);
    float* o_part = (float*)alloc((size_t)2 * 32768 * 64 * 4);
    float* l_part = (float*)alloc((size_t)2 * 32768 * 4);

    gemm_qkv_kernel<<<dim3(64, 12), 256, 0, stream>>>(h, Wq, Wk, Wv, bq, bk, bv,
                                                      Qb, Kb, Vt);
    attn_kernel<<<dim3(16, 8, 8), 256, 0, stream>>>(
        Qb, Kb, Vt, x, alpha, log_sigma, o_part, l_part);
    gemm_out_kernel<<<dim3(64, 8), 256, 0, stream>>>(o_part, l_part, Wo, bo, out);
}